// Round 14
// baseline (109.723 us; speedup 1.0000x reference)
//
#include <hip/hip_runtime.h>
#include <hip/hip_bf16.h>

#define BB 4
#define DEPTH 160
#define CC 96
#define NN 2560          // DEPTH*16
#define NHH 4
#define HD 24
#define THETA 0.6f
#define BN_EPS 1e-5f

typedef __attribute__((ext_vector_type(4))) float f32x4;
typedef __attribute__((ext_vector_type(8))) short s16x8;
typedef __attribute__((ext_vector_type(4))) short s16x4;
typedef __attribute__((ext_vector_type(2))) unsigned u32x2;
typedef __attribute__((ext_vector_type(4))) unsigned u32x4;

#if __has_builtin(__builtin_amdgcn_exp2f)
#define EXP2(x) __builtin_amdgcn_exp2f(x)
#else
#define EXP2(x) exp2f(x)
#endif

// ---------------------------------------------------------------------------
// Workspace layout (float slots):
//   wq_b  : bf16 [tap][oc][ic] 27*96*96 shorts  -> 124416 slots (r10 layout)
//   wk_b  : 124416
//   wv_b  : bf16 [oc][ic] 9216 shorts           -> 4608
//   bias_q: 96, bias_k: 96 (fp32)
//   att   : fp32 [b][n][96]                     -> 983040
//   Qb    : bf16 [bh][n][32] (hd 24..31 zeroed) -> 655360
//   Kb    : bf16 [bh][n][32]                    -> 655360
//   Vtp   : bf16 [bh][tile][s*2+dh][16 dims][32 slots] — per-64-key-tile blocked,
//           slot = vslot within half; pad dims 24..31 zeroed -> 655360
// ---------------------------------------------------------------------------
#define WS_WQ   0
#define WS_WK   124416
#define WS_WV   248832
#define WS_BQ   253440
#define WS_BK   253536
#define WS_ATT  253632
#define WS_QB   1236672
#define WS_KB   1892032
#define WS_VT   2547392

__device__ __forceinline__ short f2bf(float f) {
    unsigned u = __float_as_uint(f);
    u += 0x7fffu + ((u >> 16) & 1u);
    return (short)(u >> 16);
}
__device__ __forceinline__ unsigned bf16pk(float lo, float hi) {
    unsigned r;
    asm("v_cvt_pk_bf16_f32 %0, %1, %2" : "=v"(r) : "v"(lo), "v"(hi));
    return r;
}
// PV slot of key n within its 64-token tile (bit5 = s-half kept, low 5 permuted
// so the P B-fragment is the lane's own QK^T output).
__device__ __forceinline__ int vslot(int n) {
    return (n & 32) | (((n >> 2) & 3) << 3) | (((n >> 4) & 1) << 2) | (n & 3);
}

// Fold TCDC center-tap correction + BN scale into conv weights; bf16 [tap][oc][ic].
// The Q-instance also converts the 1x1x1 V weights (wv/wv_b non-null).
__global__ void prep_w(const float* __restrict__ w, const float* __restrict__ gamma,
                       const float* __restrict__ beta, const float* __restrict__ mean,
                       const float* __restrict__ var, short* __restrict__ w_eff,
                       float* __restrict__ bias,
                       const float* __restrict__ wv, short* __restrict__ wv_b) {
    int oc = blockIdx.x;
    int ic = threadIdx.x;
    if (ic >= CC) return;
    float scale = gamma[oc] * rsqrtf(var[oc] + BN_EPS);
    if (ic == 0) bias[oc] = beta[oc] - mean[oc] * scale;
    const float* wp = w + (oc * CC + ic) * 27;
    float kdiff = 0.f;
#pragma unroll
    for (int t = 0; t < 9; ++t) kdiff += wp[t] + wp[18 + t];
#pragma unroll
    for (int t = 0; t < 27; ++t) {
        float v = wp[t];
        if (t == 13) v -= THETA * kdiff;     // center tap (1,1,1)
        w_eff[t * (CC * CC) + oc * CC + ic] = f2bf(v * scale);
    }
    if (wv_b) wv_b[oc * CC + ic] = f2bf(wv[oc * CC + ic]);
}

// MFMA im2col conv. Block = (1 depth slice) x (oc-half); 3 waves = oct(3).
// Grid 1280 blocks -> 3.75 waves/SIMD (2x r13's TLP; the kernel is
// latency-bound per r12 counters, so wave supply is the lever).
// Each wave computes Q AND K AND V for one oc-tile x 16 tokens;
// 1 ds_read feeds 2 MFMAs; no min-blocks bound -> VGPR headroom for
// software pipelining of the unrolled 81-iteration loop.
__global__ __launch_bounds__(192) void qkv_conv(
        const float* __restrict__ x, const short* __restrict__ wq_b,
        const short* __restrict__ wk_b, const short* __restrict__ wv_b,
        const float* __restrict__ bias_q, const float* __restrict__ bias_k,
        const float* __restrict__ sgp,
        short* __restrict__ Qb, short* __restrict__ Kb, short* __restrict__ Vtp) {
    __shared__ __align__(16) short xs[49 * 104];   // slices d-1,d,d+1 + zero row
    const int b = blockIdx.y;
    const int d = blockIdx.x;
    const int z = blockIdx.z;                       // oc-half
    const int tid = threadIdx.x;

    // stage 3 slices (d-1 .. d+1), f32 -> bf16 via cvt_pk; 1152 chunks
#pragma unroll
    for (int k = 0; k < 6; ++k) {
        int c = tid + k * 192;
        int row = c / 24, ic0 = (c % 24) * 4;
        int dg = d - 1 + (row >> 4), pos = row & 15;
        u32x2 o = {0u, 0u};
        if (dg >= 0 && dg < DEPTH) {
            f32x4 v = *(const f32x4*)(x + ((size_t)(b * NN + dg * 16 + pos)) * CC + ic0);
            o[0] = bf16pk(v[0], v[1]);
            o[1] = bf16pk(v[2], v[3]);
        }
        *(u32x2*)&xs[row * 104 + ic0] = o;
    }
    if (tid < 26) *(u32x2*)&xs[48 * 104 + tid * 4] = (u32x2){0u, 0u};
    __syncthreads();

    const int w  = tid >> 6, l = tid & 63;          // w = oct
    const int j  = l & 15, g = l >> 4;
    const int oc0 = z * 48 + w * 16;
    const int hj = j >> 2, wj = j & 3;

    const short* wqlane = wq_b + (oc0 + j) * CC + 8 * g;
    const short* wklane = wk_b + (oc0 + j) * CC + 8 * g;
    const short* wvlane = wv_b + (oc0 + j) * CC + 8 * g;

    f32x4 accQ = {0,0,0,0}, accK = {0,0,0,0}, av = {0,0,0,0};

#pragma unroll
    for (int kd = 0; kd < 3; ++kd)
#pragma unroll
    for (int kh = 0; kh < 3; ++kh)
#pragma unroll
    for (int kw = 0; kw < 3; ++kw) {
        const int tap = kd * 9 + kh * 3 + kw;
        const int hh = hj + kh - 1, ww = wj + kw - 1;
        const bool valid = ((unsigned)hh < 4u) && ((unsigned)ww < 4u);
        const int row = valid ? (kd * 16 + hh * 4 + ww) : 48;      // 48 = zero row
        const short* xr = &xs[row * 104 + 8 * g];
        const short* wtq = wqlane + tap * (CC * CC);
        const short* wtk = wklane + tap * (CC * CC);
#pragma unroll
        for (int icb = 0; icb < 3; ++icb) {
            s16x8 af = *(const s16x8*)(xr + icb * 32);             // ONE ds_read
            s16x8 bq = *(const s16x8*)(wtq + icb * 32);
            s16x8 bk = *(const s16x8*)(wtk + icb * 32);
            accQ = __builtin_amdgcn_mfma_f32_16x16x32_bf16(af, bq, accQ, 0, 0, 0);
            accK = __builtin_amdgcn_mfma_f32_16x16x32_bf16(af, bk, accK, 0, 0, 0);
            if (tap == 13) {   // V rides the center tap's A-frag
                s16x8 bv = *(const s16x8*)(wvlane + icb * 32);
                av = __builtin_amdgcn_mfma_f32_16x16x32_bf16(af, bv, av, 0, 0, 0);
            }
        }
    }

    // epilogue
    const float qs = 1.4426950408889634f / sgp[0];
    const int n0 = d * 16 + 4 * g;
    const int oc = oc0 + j, h = oc / HD, hd = oc % HD;
    const float bq_ = bias_q[oc], bk_ = bias_k[oc];
    const size_t headbase = (size_t)(b * NHH + h) * NN;
    short* Qp = Qb + (headbase + n0) * 32 + hd;
    short* Kp = Kb + (headbase + n0) * 32 + hd;
#pragma unroll
    for (int r = 0; r < 4; ++r) {
        Qp[r * 32] = f2bf((accQ[r] + bq_) * qs);
        Kp[r * 32] = f2bf(accK[r] + bk_);
    }
    {
        // Vtp[bh][tile][s*2+dh][dj][slot] — tile-blocked coalesced layout
        short* Vb = Vtp + (size_t)(b * NHH + h) * (NN * 32);
        const int dh = hd >> 4, dj = hd & 15;
#pragma unroll
        for (int r = 0; r < 4; ++r) {
            int n = n0 + r;
            int wn = vslot(n & 63);
            Vb[(n >> 6) * 2048 + ((wn >> 5) * 2 + dh) * 512 + dj * 32 + (wn & 31)] = f2bf(av[r]);
        }
    }
    // zero pads once per 16-token slice (z==0, w==0 wave): 64 lanes = 4 heads x
    // 16 tokens. Qb/Kb hd 24..31; Vtp pad dims 24..31 (dh=1, dj 8..15).
    if (z == 0 && w == 0) {
        const int h2 = l >> 4;                 // 0..3
        const int n = d * 16 + (l & 15);
        const s16x8 z8 = {0, 0, 0, 0, 0, 0, 0, 0};
        *(s16x8*)(Qb + ((size_t)(b * NHH + h2) * NN + n) * 32 + 24) = z8;
        *(s16x8*)(Kb + ((size_t)(b * NHH + h2) * NN + n) * 32 + 24) = z8;
        const int wN = vslot(n & 63);
        short* pb = Vtp + (size_t)(b * NHH + h2) * (NN * 32)
                  + (n >> 6) * 2048 + ((wN >> 5) * 2 + 1) * 512 + (wN & 31);
#pragma unroll
        for (int dj = 8; dj < 16; ++dj)
            pb[dj * 32] = 0;
    }
}

// MFMA flash attention — r10 (proven): 32 q-rows/block so each wave's K/V
// loads serve TWO q-tiles; V in tile-blocked layout -> all loads coalesced 1KB.
//   QK^T = mfma(K, Qt): lane (j,g) holds scores for q-row j, keys {16m+4g+r}.
//   PV slot (g,i) = key 16*(i>>2)+4g+(i&3); V pre-stored by vslot() so the
//   B-fragment is the lane's own cvt_pk'd P (in-register, no LDS exchange).
// 4 waves, K-split x4 (each 640 keys); 4-way max-rebased LDS combine at end.
#define SOFTTILE(S0, S1, S2, S3, MX, LP, OA, OB, P0, P1) {                      \
    float v0 = fmaxf(fmaxf(S0[0], S0[1]), fmaxf(S0[2], S0[3]));                 \
    float v1 = fmaxf(fmaxf(S1[0], S1[1]), fmaxf(S1[2], S1[3]));                 \
    float v2 = fmaxf(fmaxf(S2[0], S2[1]), fmaxf(S2[2], S2[3]));                 \
    float v3 = fmaxf(fmaxf(S3[0], S3[1]), fmaxf(S3[2], S3[3]));                 \
    float vmx = fmaxf(fmaxf(v0, v1), fmaxf(v2, v3));                            \
    vmx = fmaxf(vmx, __shfl_xor(vmx, 16));                                      \
    vmx = fmaxf(vmx, __shfl_xor(vmx, 32));                                      \
    float nm = fmaxf(MX, vmx);                                                  \
    float sc = EXP2(MX - nm);                                                   \
    MX = nm;                                                                    \
    LP *= sc; OA *= sc; OB *= sc;                                               \
    float p00 = EXP2(S0[0] - MX), p01 = EXP2(S0[1] - MX);                       \
    float p02 = EXP2(S0[2] - MX), p03 = EXP2(S0[3] - MX);                       \
    float p10 = EXP2(S1[0] - MX), p11 = EXP2(S1[1] - MX);                       \
    float p12 = EXP2(S1[2] - MX), p13 = EXP2(S1[3] - MX);                       \
    float p20 = EXP2(S2[0] - MX), p21 = EXP2(S2[1] - MX);                       \
    float p22 = EXP2(S2[2] - MX), p23 = EXP2(S2[3] - MX);                       \
    float p30 = EXP2(S3[0] - MX), p31 = EXP2(S3[1] - MX);                       \
    float p32 = EXP2(S3[2] - MX), p33 = EXP2(S3[3] - MX);                       \
    LP += (((p00 + p01) + (p02 + p03)) + ((p10 + p11) + (p12 + p13)))           \
        + (((p20 + p21) + (p22 + p23)) + ((p30 + p31) + (p32 + p33)));          \
    u32x4 w0_ = { bf16pk(p00, p01), bf16pk(p02, p03),                           \
                  bf16pk(p10, p11), bf16pk(p12, p13) };                         \
    u32x4 w1_ = { bf16pk(p20, p21), bf16pk(p22, p23),                           \
                  bf16pk(p30, p31), bf16pk(p32, p33) };                         \
    P0 = __builtin_bit_cast(s16x8, w0_);                                        \
    P1 = __builtin_bit_cast(s16x8, w1_);                                        \
}

__global__ __launch_bounds__(256) void attn_kernel(
        const short* __restrict__ Qb, const short* __restrict__ Kb,
        const short* __restrict__ Vtp, float* __restrict__ att) {
    __shared__ __align__(16) float comb[3][64][20];
    const int bh = blockIdx.x & 15;            // pins bh pairs per XCD for L2 reuse
    const int q0 = (blockIdx.x >> 4) * 32;
    const int b = bh >> 2, h = bh & 3;
    const int tid = threadIdx.x, wvid = tid >> 6, l = tid & 63;
    const int j = l & 15, g = l >> 4;

    const s16x8 qf0 = *(const s16x8*)(Qb + ((size_t)bh * NN + q0 + j) * 32 + 8 * g);
    const s16x8 qf1 = *(const s16x8*)(Qb + ((size_t)bh * NN + q0 + 16 + j) * 32 + 8 * g);
    const short* Kbase = Kb  + (size_t)bh * NN * 32 + (size_t)j * 32 + 8 * g;
    const short* Vbase = Vtp + (size_t)bh * NN * 32 + (size_t)j * 32 + 8 * g;

    f32x4 oA0 = {0,0,0,0}, oB0 = {0,0,0,0};    // q-tile 0: O^T dims 4g.. / 16+4g..
    f32x4 oA1 = {0,0,0,0}, oB1 = {0,0,0,0};    // q-tile 1
    float mx0 = -1e30f, lp0 = 0.f, mx1 = -1e30f, lp1 = 0.f;
    const f32x4 z = {0,0,0,0};

    const int tbeg = wvid * (NN / 4);
    const int tend = tbeg + NN / 4;            // 640 keys, 10 tiles per wave

    for (int t0 = tbeg; t0 < tend; t0 += 64) {
        const short* kp = Kbase + (size_t)t0 * 32;
        s16x8 k0 = *(const s16x8*)(kp);
        s16x8 k1 = *(const s16x8*)(kp + 512);
        s16x8 k2 = *(const s16x8*)(kp + 1024);
        s16x8 k3 = *(const s16x8*)(kp + 1536);
        const short* vp = Vbase + (size_t)t0 * 32;     // tile base: t0/64*2048
        s16x8 vA0 = *(const s16x8*)(vp);               // (s0,d0)
        s16x8 vB0 = *(const s16x8*)(vp + 512);         // (s0,d1)
        s16x8 vA1 = *(const s16x8*)(vp + 1024);        // (s1,d0)
        s16x8 vB1 = *(const s16x8*)(vp + 1536);        // (s1,d1)

        f32x4 s0 = __builtin_amdgcn_mfma_f32_16x16x32_bf16(k0, qf0, z, 0, 0, 0);
        f32x4 s1 = __builtin_amdgcn_mfma_f32_16x16x32_bf16(k1, qf0, z, 0, 0, 0);
        f32x4 s2 = __builtin_amdgcn_mfma_f32_16x16x32_bf16(k2, qf0, z, 0, 0, 0);
        f32x4 s3 = __builtin_amdgcn_mfma_f32_16x16x32_bf16(k3, qf0, z, 0, 0, 0);
        s16x8 P00, P01;
        SOFTTILE(s0, s1, s2, s3, mx0, lp0, oA0, oB0, P00, P01)

        f32x4 t0s = __builtin_amdgcn_mfma_f32_16x16x32_bf16(k0, qf1, z, 0, 0, 0);
        f32x4 t1s = __builtin_amdgcn_mfma_f32_16x16x32_bf16(k1, qf1, z, 0, 0, 0);
        f32x4 t2s = __builtin_amdgcn_mfma_f32_16x16x32_bf16(k2, qf1, z, 0, 0, 0);
        f32x4 t3s = __builtin_amdgcn_mfma_f32_16x16x32_bf16(k3, qf1, z, 0, 0, 0);
        s16x8 P10, P11;
        SOFTTILE(t0s, t1s, t2s, t3s, mx1, lp1, oA1, oB1, P10, P11)

        oA0 = __builtin_amdgcn_mfma_f32_16x16x32_bf16(vA0, P00, oA0, 0, 0, 0);
        oA0 = __builtin_amdgcn_mfma_f32_16x16x32_bf16(vA1, P01, oA0, 0, 0, 0);
        oB0 = __builtin_amdgcn_mfma_f32_16x16x32_bf16(vB0, P00, oB0, 0, 0, 0);
        oB0 = __builtin_amdgcn_mfma_f32_16x16x32_bf16(vB1, P01, oB0, 0, 0, 0);
        oA1 = __builtin_amdgcn_mfma_f32_16x16x32_bf16(vA0, P10, oA1, 0, 0, 0);
        oA1 = __builtin_amdgcn_mfma_f32_16x16x32_bf16(vA1, P11, oA1, 0, 0, 0);
        oB1 = __builtin_amdgcn_mfma_f32_16x16x32_bf16(vB0, P10, oB1, 0, 0, 0);
        oB1 = __builtin_amdgcn_mfma_f32_16x16x32_bf16(vB1, P11, oB1, 0, 0, 0);
    }

    // row-sum lp across the 4 g-lanes
    lp0 += __shfl_xor(lp0, 16); lp0 += __shfl_xor(lp0, 32);
    lp1 += __shfl_xor(lp1, 16); lp1 += __shfl_xor(lp1, 32);

    if (wvid != 0) {
        float* cp = comb[wvid - 1][l];
        cp[0] = mx0; cp[1] = lp0; cp[2] = mx1; cp[3] = lp1;
        *(f32x4*)(cp + 4)  = oA0;
        *(f32x4*)(cp + 8)  = oB0;
        *(f32x4*)(cp + 12) = oA1;
        *(f32x4*)(cp + 16) = oB1;
    }
    __syncthreads();
    if (wvid != 0) return;

    // 4-way max-rebased combine (both q-tiles)
#pragma unroll
    for (int wv = 0; wv < 3; ++wv) {
        const float* cp = comb[wv][l];
        {
            float mb = cp[0], lb = cp[1];
            f32x4 oAb = *(const f32x4*)(cp + 4);
            f32x4 oBb = *(const f32x4*)(cp + 8);
            float mm = fmaxf(mx0, mb);
            float sa = EXP2(mx0 - mm), sb = EXP2(mb - mm);
            mx0 = mm;
            lp0 = lp0 * sa + lb * sb;
            oA0 = oA0 * sa + oAb * sb;
            oB0 = oB0 * sa + oBb * sb;
        }
        {
            float mb = cp[2], lb = cp[3];
            f32x4 oAb = *(const f32x4*)(cp + 12);
            f32x4 oBb = *(const f32x4*)(cp + 16);
            float mm = fmaxf(mx1, mb);
            float sa = EXP2(mx1 - mm), sb = EXP2(mb - mm);
            mx1 = mm;
            lp1 = lp1 * sa + lb * sb;
            oA1 = oA1 * sa + oAb * sb;
            oB1 = oB1 * sa + oBb * sb;
        }
    }

    const float rl0 = 1.f / lp0, rl1 = 1.f / lp1;
    f32x4 rA0 = oA0 * rl0, rB0 = oB0 * rl0;
    f32x4 rA1 = oA1 * rl1, rB1 = oB1 * rl1;

    float* op0 = att + ((size_t)b * NN + q0 + j) * CC + h * HD;
    float* op1 = att + ((size_t)b * NN + q0 + 16 + j) * CC + h * HD;
    *(f32x4*)(op0 + 4 * g) = rA0;
    *(f32x4*)(op1 + 4 * g) = rA1;
    if (g < 2) {
        *(f32x4*)(op0 + 16 + 4 * g) = rB0;
        *(f32x4*)(op1 + 16 + 4 * g) = rB1;
    }
}

// out[t,c] = bo[c] + sum_cp att[t,cp] * wo[c,cp]
__global__ __launch_bounds__(256) void proj_kernel(
        const float* __restrict__ att, const float* __restrict__ wo,
        const float* __restrict__ bo, float* __restrict__ out) {
    __shared__ float wt[CC][CC + 1];   // wt[cp][c] = wo[c][cp], padded
    for (int i = threadIdx.x; i < CC * CC; i += 256) {
        int c = i / CC, cp = i % CC;
        wt[cp][c] = wo[i];
    }
    __syncthreads();
    int idx = blockIdx.x * 256 + threadIdx.x;
    int c = idx % CC;
    int t = idx / CC;
    const float* ar = att + (size_t)t * CC;
    float s = bo[c];
#pragma unroll 8
    for (int cp = 0; cp < CC; ++cp) s += ar[cp] * wt[cp][c];
    out[idx] = s;
}

extern "C" void kernel_launch(void* const* d_in, const int* in_sizes, int n_in,
                              void* d_out, int out_size, void* d_ws, size_t ws_size,
                              hipStream_t stream) {
    const float* x     = (const float*)d_in[0];
    const float* sg    = (const float*)d_in[1];
    const float* wq    = (const float*)d_in[2];
    const float* bnq_g = (const float*)d_in[3];
    const float* bnq_b = (const float*)d_in[4];
    const float* bnq_m = (const float*)d_in[5];
    const float* bnq_v = (const float*)d_in[6];
    const float* wk    = (const float*)d_in[7];
    const float* bnk_g = (const float*)d_in[8];
    const float* bnk_b = (const float*)d_in[9];
    const float* bnk_m = (const float*)d_in[10];
    const float* bnk_v = (const float*)d_in[11];
    const float* wv    = (const float*)d_in[12];
    const float* wo    = (const float*)d_in[13];
    const float* bo    = (const float*)d_in[14];

    float* ws = (float*)d_ws;
    short* wq_b   = (short*)(ws + WS_WQ);
    short* wk_b   = (short*)(ws + WS_WK);
    short* wv_b   = (short*)(ws + WS_WV);
    float* bias_q = ws + WS_BQ;
    float* bias_k = ws + WS_BK;
    float* attw   = ws + WS_ATT;
    short* Qb     = (short*)(ws + WS_QB);
    short* Kb     = (short*)(ws + WS_KB);
    short* Vtp    = (short*)(ws + WS_VT);

    prep_w<<<dim3(CC), dim3(128), 0, stream>>>(wq, bnq_g, bnq_b, bnq_m, bnq_v, wq_b, bias_q,
                                               wv, wv_b);
    prep_w<<<dim3(CC), dim3(128), 0, stream>>>(wk, bnk_g, bnk_b, bnk_m, bnk_v, wk_b, bias_k,
                                               nullptr, nullptr);

    qkv_conv<<<dim3(DEPTH, BB, 2), dim3(192), 0, stream>>>(
        x, wq_b, wk_b, wv_b, bias_q, bias_k, sg, Qb, Kb, Vtp);

    attn_kernel<<<dim3(NN / 32 * 16), dim3(256), 0, stream>>>(Qb, Kb, Vtp, attw);

    proj_kernel<<<dim3((BB * NN * CC) / 256), dim3(256), 0, stream>>>(attw, wo, bo, (float*)d_out);
}

// Round 15
// 96.271 us; speedup vs baseline: 1.1397x; 1.1397x over previous
//
#include <hip/hip_runtime.h>
#include <hip/hip_bf16.h>

#define BB 4
#define DEPTH 160
#define CC 96
#define NN 2560          // DEPTH*16
#define NHH 4
#define HD 24
#define THETA 0.6f
#define BN_EPS 1e-5f

typedef __attribute__((ext_vector_type(4))) float f32x4;
typedef __attribute__((ext_vector_type(8))) short s16x8;
typedef __attribute__((ext_vector_type(4))) short s16x4;
typedef __attribute__((ext_vector_type(2))) unsigned u32x2;
typedef __attribute__((ext_vector_type(4))) unsigned u32x4;

#if __has_builtin(__builtin_amdgcn_exp2f)
#define EXP2(x) __builtin_amdgcn_exp2f(x)
#else
#define EXP2(x) exp2f(x)
#endif

// ---------------------------------------------------------------------------
// Workspace layout (float slots):
//   wq_b  : bf16 [tap][oc][ic] 27*96*96 shorts  -> 124416 slots (r10 layout)
//   wk_b  : 124416
//   wv_b  : bf16 [oc][ic] 9216 shorts           -> 4608
//   bias_q: 96, bias_k: 96 (fp32)
//   att   : fp32 [b][n][96]                     -> 983040
//   Qb    : bf16 [bh][n][32] (hd 24..31 zeroed) -> 655360
//   Kb    : bf16 [bh][n][32]                    -> 655360
//   Vtp   : bf16 [bh][tile][s*2+dh][16 dims][32 slots] — per-64-key-tile blocked,
//           slot = vslot within half; pad dims 24..31 zeroed -> 655360
// ---------------------------------------------------------------------------
#define WS_WQ   0
#define WS_WK   124416
#define WS_WV   248832
#define WS_BQ   253440
#define WS_BK   253536
#define WS_ATT  253632
#define WS_QB   1236672
#define WS_KB   1892032
#define WS_VT   2547392

__device__ __forceinline__ short f2bf(float f) {
    unsigned u = __float_as_uint(f);
    u += 0x7fffu + ((u >> 16) & 1u);
    return (short)(u >> 16);
}
__device__ __forceinline__ unsigned bf16pk(float lo, float hi) {
    unsigned r;
    asm("v_cvt_pk_bf16_f32 %0, %1, %2" : "=v"(r) : "v"(lo), "v"(hi));
    return r;
}
// PV slot of key n within its 64-token tile (bit5 = s-half kept, low 5 permuted
// so the P B-fragment is the lane's own QK^T output).
__device__ __forceinline__ int vslot(int n) {
    return (n & 32) | (((n >> 2) & 3) << 3) | (((n >> 4) & 1) << 2) | (n & 3);
}

// Fold TCDC center-tap correction + BN scale into conv weights; bf16 [tap][oc][ic].
// The Q-instance also converts the 1x1x1 V weights (wv/wv_b non-null).
__global__ void prep_w(const float* __restrict__ w, const float* __restrict__ gamma,
                       const float* __restrict__ beta, const float* __restrict__ mean,
                       const float* __restrict__ var, short* __restrict__ w_eff,
                       float* __restrict__ bias,
                       const float* __restrict__ wv, short* __restrict__ wv_b) {
    int oc = blockIdx.x;
    int ic = threadIdx.x;
    if (ic >= CC) return;
    float scale = gamma[oc] * rsqrtf(var[oc] + BN_EPS);
    if (ic == 0) bias[oc] = beta[oc] - mean[oc] * scale;
    const float* wp = w + (oc * CC + ic) * 27;
    float kdiff = 0.f;
#pragma unroll
    for (int t = 0; t < 9; ++t) kdiff += wp[t] + wp[18 + t];
#pragma unroll
    for (int t = 0; t < 27; ++t) {
        float v = wp[t];
        if (t == 13) v -= THETA * kdiff;     // center tap (1,1,1)
        w_eff[t * (CC * CC) + oc * CC + ic] = f2bf(v * scale);
    }
    if (wv_b) wv_b[oc * CC + ic] = f2bf(wv[oc * CC + ic]);
}

// MFMA im2col conv. Block = (2 depth slices) x (oc-half); 3 waves = oct(3).
// Each wave computes Q AND K AND V for one oc-tile across BOTH token slices.
// Weight B-fragments are EXPLICITLY double-buffered in registers: tap t+1's
// 6 fragments are loaded before tap t's MFMAs execute, forcing the compiler
// to keep 6 global loads in flight a full tap (~170 cy) ahead (r12/r14
// counters proved it never does this on its own: VGPR=40, all pipes <8%).
__global__ __launch_bounds__(192) void qkv_conv(
        const float* __restrict__ x, const short* __restrict__ wq_b,
        const short* __restrict__ wk_b, const short* __restrict__ wv_b,
        const float* __restrict__ bias_q, const float* __restrict__ bias_k,
        const float* __restrict__ sgp,
        short* __restrict__ Qb, short* __restrict__ Kb, short* __restrict__ Vtp) {
    __shared__ __align__(16) short xs[65 * 104];   // 64 rows + zero row, stride 104
    const int b = blockIdx.y;
    const int d0 = blockIdx.x * 2;
    const int z = blockIdx.z;                       // oc-half
    const int tid = threadIdx.x;

    // stage 4 slices (d0-1 .. d0+2), f32 -> bf16 via cvt_pk; 1536 chunks
#pragma unroll
    for (int k = 0; k < 8; ++k) {
        int c = tid + k * 192;
        int row = c / 24, ic0 = (c % 24) * 4;
        int dg = d0 - 1 + (row >> 4), pos = row & 15;
        u32x2 o = {0u, 0u};
        if (dg >= 0 && dg < DEPTH) {
            f32x4 v = *(const f32x4*)(x + ((size_t)(b * NN + dg * 16 + pos)) * CC + ic0);
            o[0] = bf16pk(v[0], v[1]);
            o[1] = bf16pk(v[2], v[3]);
        }
        *(u32x2*)&xs[row * 104 + ic0] = o;
    }
    if (tid < 26) *(u32x2*)&xs[64 * 104 + tid * 4] = (u32x2){0u, 0u};
    __syncthreads();

    const int w  = tid >> 6, l = tid & 63;          // w = oct
    const int j  = l & 15, g = l >> 4;
    const int oc0 = z * 48 + w * 16;
    const int hj = j >> 2, wj = j & 3;

    const short* wqlane = wq_b + (oc0 + j) * CC + 8 * g;
    const short* wklane = wk_b + (oc0 + j) * CC + 8 * g;
    const short* wvlane = wv_b + (oc0 + j) * CC + 8 * g;

    f32x4 accQA = {0,0,0,0}, accQB = {0,0,0,0};
    f32x4 accKA = {0,0,0,0}, accKB = {0,0,0,0};
    f32x4 avA   = {0,0,0,0}, avB   = {0,0,0,0};

    // register double-buffer: current / next tap weight fragments
    s16x8 wqc[3], wkc[3], wqn[3], wkn[3];
#pragma unroll
    for (int icb = 0; icb < 3; ++icb) {
        wqc[icb] = *(const s16x8*)(wqlane + icb * 32);     // tap 0
        wkc[icb] = *(const s16x8*)(wklane + icb * 32);
    }

#pragma unroll
    for (int tap = 0; tap < 27; ++tap) {
        // issue next tap's weight loads FIRST (land during this tap's compute)
        if (tap < 26) {
#pragma unroll
            for (int icb = 0; icb < 3; ++icb) {
                wqn[icb] = *(const s16x8*)(wqlane + (tap + 1) * (CC * CC) + icb * 32);
                wkn[icb] = *(const s16x8*)(wklane + (tap + 1) * (CC * CC) + icb * 32);
            }
        }
        const int kd = tap / 9, kh = (tap / 3) % 3, kw = tap % 3;
        const int hh = hj + kh - 1, ww = wj + kw - 1;
        const bool valid = ((unsigned)hh < 4u) && ((unsigned)ww < 4u);
        const int rA = valid ? (kd * 16 + hh * 4 + ww) : 64;       // slice t=0
        const int rB = valid ? ((1 + kd) * 16 + hh * 4 + ww) : 64; // slice t=1
        const short* xrA = &xs[rA * 104 + 8 * g];
        const short* xrB = &xs[rB * 104 + 8 * g];
#pragma unroll
        for (int icb = 0; icb < 3; ++icb) {
            s16x8 afA = *(const s16x8*)(xrA + icb * 32);
            s16x8 afB = *(const s16x8*)(xrB + icb * 32);
            accQA = __builtin_amdgcn_mfma_f32_16x16x32_bf16(afA, wqc[icb], accQA, 0, 0, 0);
            accQB = __builtin_amdgcn_mfma_f32_16x16x32_bf16(afB, wqc[icb], accQB, 0, 0, 0);
            accKA = __builtin_amdgcn_mfma_f32_16x16x32_bf16(afA, wkc[icb], accKA, 0, 0, 0);
            accKB = __builtin_amdgcn_mfma_f32_16x16x32_bf16(afB, wkc[icb], accKB, 0, 0, 0);
            if (tap == 13) {   // V rides the center tap's A-frags
                s16x8 bv = *(const s16x8*)(wvlane + icb * 32);
                avA = __builtin_amdgcn_mfma_f32_16x16x32_bf16(afA, bv, avA, 0, 0, 0);
                avB = __builtin_amdgcn_mfma_f32_16x16x32_bf16(afB, bv, avB, 0, 0, 0);
            }
        }
        if (tap < 26) {
#pragma unroll
            for (int icb = 0; icb < 3; ++icb) {
                wqc[icb] = wqn[icb];
                wkc[icb] = wkn[icb];
            }
        }
    }

    // epilogue
    const float qs = 1.4426950408889634f / sgp[0];
    const int oc = oc0 + j, h = oc / HD, hd = oc % HD;
    const float bq_ = bias_q[oc], bk_ = bias_k[oc];
    const size_t headbase = (size_t)(b * NHH + h) * NN;
    short* QpA = Qb + (headbase + (d0 + 0) * 16 + 4 * g) * 32 + hd;
    short* QpB = Qb + (headbase + (d0 + 1) * 16 + 4 * g) * 32 + hd;
    short* KpA = Kb + (headbase + (d0 + 0) * 16 + 4 * g) * 32 + hd;
    short* KpB = Kb + (headbase + (d0 + 1) * 16 + 4 * g) * 32 + hd;
#pragma unroll
    for (int r = 0; r < 4; ++r) {
        QpA[r * 32] = f2bf((accQA[r] + bq_) * qs);
        QpB[r * 32] = f2bf((accQB[r] + bq_) * qs);
        KpA[r * 32] = f2bf(accKA[r] + bk_);
        KpB[r * 32] = f2bf(accKB[r] + bk_);
    }
    {
        // Vtp[bh][tile][s*2+dh][dj][slot] — tile-blocked coalesced layout
        short* Vb = Vtp + (size_t)(b * NHH + h) * (NN * 32);
        const int dh = hd >> 4, dj = hd & 15;
#pragma unroll
        for (int r = 0; r < 4; ++r) {
            int nA = d0 * 16 + 4 * g + r;
            int nB = nA + 16;
            int wA = vslot(nA & 63), wB = vslot(nB & 63);
            Vb[(nA >> 6) * 2048 + ((wA >> 5) * 2 + dh) * 512 + dj * 32 + (wA & 31)] = f2bf(avA[r]);
            Vb[(nB >> 6) * 2048 + ((wB >> 5) * 2 + dh) * 512 + dj * 32 + (wB & 31)] = f2bf(avB[r]);
        }
    }
    // zero pads once per token-block (z==0, w==0 wave):
    //   Qb/Kb hd 24..31 (contracted in attn MFMA); Vtp pad dims 24..31 (dh=1, dj 8..15)
    if (z == 0 && w == 0) {
        const int n = (d0 + ((l >> 4) & 1)) * 16 + (l & 15);
        const s16x8 z8 = {0, 0, 0, 0, 0, 0, 0, 0};
#pragma unroll
        for (int it = 0; it < 2; ++it) {
            int h2 = (l >> 5) + 2 * it;
            *(s16x8*)(Qb + ((size_t)(b * NHH + h2) * NN + n) * 32 + 24) = z8;
            *(s16x8*)(Kb + ((size_t)(b * NHH + h2) * NN + n) * 32 + 24) = z8;
        }
        const int wN = vslot(n & 63);
#pragma unroll
        for (int it2 = 0; it2 < 2; ++it2) {
            int h3 = it2 * 2 + (l >> 5);
            short* pb = Vtp + (size_t)(b * NHH + h3) * (NN * 32)
                      + (n >> 6) * 2048 + ((wN >> 5) * 2 + 1) * 512 + (wN & 31);
#pragma unroll
            for (int dj = 8; dj < 16; ++dj)
                pb[dj * 32] = 0;
        }
    }
}

// MFMA flash attention — r10 (proven): 32 q-rows/block so each wave's K/V
// loads serve TWO q-tiles; V in tile-blocked layout -> all loads coalesced 1KB.
//   QK^T = mfma(K, Qt): lane (j,g) holds scores for q-row j, keys {16m+4g+r}.
//   PV slot (g,i) = key 16*(i>>2)+4g+(i&3); V pre-stored by vslot() so the
//   B-fragment is the lane's own cvt_pk'd P (in-register, no LDS exchange).
// 4 waves, K-split x4 (each 640 keys); 4-way max-rebased LDS combine at end.
#define SOFTTILE(S0, S1, S2, S3, MX, LP, OA, OB, P0, P1) {                      \
    float v0 = fmaxf(fmaxf(S0[0], S0[1]), fmaxf(S0[2], S0[3]));                 \
    float v1 = fmaxf(fmaxf(S1[0], S1[1]), fmaxf(S1[2], S1[3]));                 \
    float v2 = fmaxf(fmaxf(S2[0], S2[1]), fmaxf(S2[2], S2[3]));                 \
    float v3 = fmaxf(fmaxf(S3[0], S3[1]), fmaxf(S3[2], S3[3]));                 \
    float vmx = fmaxf(fmaxf(v0, v1), fmaxf(v2, v3));                            \
    vmx = fmaxf(vmx, __shfl_xor(vmx, 16));                                      \
    vmx = fmaxf(vmx, __shfl_xor(vmx, 32));                                      \
    float nm = fmaxf(MX, vmx);                                                  \
    float sc = EXP2(MX - nm);                                                   \
    MX = nm;                                                                    \
    LP *= sc; OA *= sc; OB *= sc;                                               \
    float p00 = EXP2(S0[0] - MX), p01 = EXP2(S0[1] - MX);                       \
    float p02 = EXP2(S0[2] - MX), p03 = EXP2(S0[3] - MX);                       \
    float p10 = EXP2(S1[0] - MX), p11 = EXP2(S1[1] - MX);                       \
    float p12 = EXP2(S1[2] - MX), p13 = EXP2(S1[3] - MX);                       \
    float p20 = EXP2(S2[0] - MX), p21 = EXP2(S2[1] - MX);                       \
    float p22 = EXP2(S2[2] - MX), p23 = EXP2(S2[3] - MX);                       \
    float p30 = EXP2(S3[0] - MX), p31 = EXP2(S3[1] - MX);                       \
    float p32 = EXP2(S3[2] - MX), p33 = EXP2(S3[3] - MX);                       \
    LP += (((p00 + p01) + (p02 + p03)) + ((p10 + p11) + (p12 + p13)))           \
        + (((p20 + p21) + (p22 + p23)) + ((p30 + p31) + (p32 + p33)));          \
    u32x4 w0_ = { bf16pk(p00, p01), bf16pk(p02, p03),                           \
                  bf16pk(p10, p11), bf16pk(p12, p13) };                         \
    u32x4 w1_ = { bf16pk(p20, p21), bf16pk(p22, p23),                           \
                  bf16pk(p30, p31), bf16pk(p32, p33) };                         \
    P0 = __builtin_bit_cast(s16x8, w0_);                                        \
    P1 = __builtin_bit_cast(s16x8, w1_);                                        \
}

__global__ __launch_bounds__(256) void attn_kernel(
        const short* __restrict__ Qb, const short* __restrict__ Kb,
        const short* __restrict__ Vtp, float* __restrict__ att) {
    __shared__ __align__(16) float comb[3][64][20];
    const int bh = blockIdx.x & 15;            // pins bh pairs per XCD for L2 reuse
    const int q0 = (blockIdx.x >> 4) * 32;
    const int b = bh >> 2, h = bh & 3;
    const int tid = threadIdx.x, wvid = tid >> 6, l = tid & 63;
    const int j = l & 15, g = l >> 4;

    const s16x8 qf0 = *(const s16x8*)(Qb + ((size_t)bh * NN + q0 + j) * 32 + 8 * g);
    const s16x8 qf1 = *(const s16x8*)(Qb + ((size_t)bh * NN + q0 + 16 + j) * 32 + 8 * g);
    const short* Kbase = Kb  + (size_t)bh * NN * 32 + (size_t)j * 32 + 8 * g;
    const short* Vbase = Vtp + (size_t)bh * NN * 32 + (size_t)j * 32 + 8 * g;

    f32x4 oA0 = {0,0,0,0}, oB0 = {0,0,0,0};    // q-tile 0: O^T dims 4g.. / 16+4g..
    f32x4 oA1 = {0,0,0,0}, oB1 = {0,0,0,0};    // q-tile 1
    float mx0 = -1e30f, lp0 = 0.f, mx1 = -1e30f, lp1 = 0.f;
    const f32x4 z = {0,0,0,0};

    const int tbeg = wvid * (NN / 4);
    const int tend = tbeg + NN / 4;            // 640 keys, 10 tiles per wave

    for (int t0 = tbeg; t0 < tend; t0 += 64) {
        const short* kp = Kbase + (size_t)t0 * 32;
        s16x8 k0 = *(const s16x8*)(kp);
        s16x8 k1 = *(const s16x8*)(kp + 512);
        s16x8 k2 = *(const s16x8*)(kp + 1024);
        s16x8 k3 = *(const s16x8*)(kp + 1536);
        const short* vp = Vbase + (size_t)t0 * 32;     // tile base: t0/64*2048
        s16x8 vA0 = *(const s16x8*)(vp);               // (s0,d0)
        s16x8 vB0 = *(const s16x8*)(vp + 512);         // (s0,d1)
        s16x8 vA1 = *(const s16x8*)(vp + 1024);        // (s1,d0)
        s16x8 vB1 = *(const s16x8*)(vp + 1536);        // (s1,d1)

        f32x4 s0 = __builtin_amdgcn_mfma_f32_16x16x32_bf16(k0, qf0, z, 0, 0, 0);
        f32x4 s1 = __builtin_amdgcn_mfma_f32_16x16x32_bf16(k1, qf0, z, 0, 0, 0);
        f32x4 s2 = __builtin_amdgcn_mfma_f32_16x16x32_bf16(k2, qf0, z, 0, 0, 0);
        f32x4 s3 = __builtin_amdgcn_mfma_f32_16x16x32_bf16(k3, qf0, z, 0, 0, 0);
        s16x8 P00, P01;
        SOFTTILE(s0, s1, s2, s3, mx0, lp0, oA0, oB0, P00, P01)

        f32x4 t0s = __builtin_amdgcn_mfma_f32_16x16x32_bf16(k0, qf1, z, 0, 0, 0);
        f32x4 t1s = __builtin_amdgcn_mfma_f32_16x16x32_bf16(k1, qf1, z, 0, 0, 0);
        f32x4 t2s = __builtin_amdgcn_mfma_f32_16x16x32_bf16(k2, qf1, z, 0, 0, 0);
        f32x4 t3s = __builtin_amdgcn_mfma_f32_16x16x32_bf16(k3, qf1, z, 0, 0, 0);
        s16x8 P10, P11;
        SOFTTILE(t0s, t1s, t2s, t3s, mx1, lp1, oA1, oB1, P10, P11)

        oA0 = __builtin_amdgcn_mfma_f32_16x16x32_bf16(vA0, P00, oA0, 0, 0, 0);
        oA0 = __builtin_amdgcn_mfma_f32_16x16x32_bf16(vA1, P01, oA0, 0, 0, 0);
        oB0 = __builtin_amdgcn_mfma_f32_16x16x32_bf16(vB0, P00, oB0, 0, 0, 0);
        oB0 = __builtin_amdgcn_mfma_f32_16x16x32_bf16(vB1, P01, oB0, 0, 0, 0);
        oA1 = __builtin_amdgcn_mfma_f32_16x16x32_bf16(vA0, P10, oA1, 0, 0, 0);
        oA1 = __builtin_amdgcn_mfma_f32_16x16x32_bf16(vA1, P11, oA1, 0, 0, 0);
        oB1 = __builtin_amdgcn_mfma_f32_16x16x32_bf16(vB0, P10, oB1, 0, 0, 0);
        oB1 = __builtin_amdgcn_mfma_f32_16x16x32_bf16(vB1, P11, oB1, 0, 0, 0);
    }

    // row-sum lp across the 4 g-lanes
    lp0 += __shfl_xor(lp0, 16); lp0 += __shfl_xor(lp0, 32);
    lp1 += __shfl_xor(lp1, 16); lp1 += __shfl_xor(lp1, 32);

    if (wvid != 0) {
        float* cp = comb[wvid - 1][l];
        cp[0] = mx0; cp[1] = lp0; cp[2] = mx1; cp[3] = lp1;
        *(f32x4*)(cp + 4)  = oA0;
        *(f32x4*)(cp + 8)  = oB0;
        *(f32x4*)(cp + 12) = oA1;
        *(f32x4*)(cp + 16) = oB1;
    }
    __syncthreads();
    if (wvid != 0) return;

    // 4-way max-rebased combine (both q-tiles)
#pragma unroll
    for (int wv = 0; wv < 3; ++wv) {
        const float* cp = comb[wv][l];
        {
            float mb = cp[0], lb = cp[1];
            f32x4 oAb = *(const f32x4*)(cp + 4);
            f32x4 oBb = *(const f32x4*)(cp + 8);
            float mm = fmaxf(mx0, mb);
            float sa = EXP2(mx0 - mm), sb = EXP2(mb - mm);
            mx0 = mm;
            lp0 = lp0 * sa + lb * sb;
            oA0 = oA0 * sa + oAb * sb;
            oB0 = oB0 * sa + oBb * sb;
        }
        {
            float mb = cp[2], lb = cp[3];
            f32x4 oAb = *(const f32x4*)(cp + 12);
            f32x4 oBb = *(const f32x4*)(cp + 16);
            float mm = fmaxf(mx1, mb);
            float sa = EXP2(mx1 - mm), sb = EXP2(mb - mm);
            mx1 = mm;
            lp1 = lp1 * sa + lb * sb;
            oA1 = oA1 * sa + oAb * sb;
            oB1 = oB1 * sa + oBb * sb;
        }
    }

    const float rl0 = 1.f / lp0, rl1 = 1.f / lp1;
    f32x4 rA0 = oA0 * rl0, rB0 = oB0 * rl0;
    f32x4 rA1 = oA1 * rl1, rB1 = oB1 * rl1;

    float* op0 = att + ((size_t)b * NN + q0 + j) * CC + h * HD;
    float* op1 = att + ((size_t)b * NN + q0 + 16 + j) * CC + h * HD;
    *(f32x4*)(op0 + 4 * g) = rA0;
    *(f32x4*)(op1 + 4 * g) = rA1;
    if (g < 2) {
        *(f32x4*)(op0 + 16 + 4 * g) = rB0;
        *(f32x4*)(op1 + 16 + 4 * g) = rB1;
    }
}

// out[t,c] = bo[c] + sum_cp att[t,cp] * wo[c,cp]
__global__ __launch_bounds__(256) void proj_kernel(
        const float* __restrict__ att, const float* __restrict__ wo,
        const float* __restrict__ bo, float* __restrict__ out) {
    __shared__ float wt[CC][CC + 1];   // wt[cp][c] = wo[c][cp], padded
    for (int i = threadIdx.x; i < CC * CC; i += 256) {
        int c = i / CC, cp = i % CC;
        wt[cp][c] = wo[i];
    }
    __syncthreads();
    int idx = blockIdx.x * 256 + threadIdx.x;
    int c = idx % CC;
    int t = idx / CC;
    const float* ar = att + (size_t)t * CC;
    float s = bo[c];
#pragma unroll 8
    for (int cp = 0; cp < CC; ++cp) s += ar[cp] * wt[cp][c];
    out[idx] = s;
}

extern "C" void kernel_launch(void* const* d_in, const int* in_sizes, int n_in,
                              void* d_out, int out_size, void* d_ws, size_t ws_size,
                              hipStream_t stream) {
    const float* x     = (const float*)d_in[0];
    const float* sg    = (const float*)d_in[1];
    const float* wq    = (const float*)d_in[2];
    const float* bnq_g = (const float*)d_in[3];
    const float* bnq_b = (const float*)d_in[4];
    const float* bnq_m = (const float*)d_in[5];
    const float* bnq_v = (const float*)d_in[6];
    const float* wk    = (const float*)d_in[7];
    const float* bnk_g = (const float*)d_in[8];
    const float* bnk_b = (const float*)d_in[9];
    const float* bnk_m = (const float*)d_in[10];
    const float* bnk_v = (const float*)d_in[11];
    const float* wv    = (const float*)d_in[12];
    const float* wo    = (const float*)d_in[13];
    const float* bo    = (const float*)d_in[14];

    float* ws = (float*)d_ws;
    short* wq_b   = (short*)(ws + WS_WQ);
    short* wk_b   = (short*)(ws + WS_WK);
    short* wv_b   = (short*)(ws + WS_WV);
    float* bias_q = ws + WS_BQ;
    float* bias_k = ws + WS_BK;
    float* attw   = ws + WS_ATT;
    short* Qb     = (short*)(ws + WS_QB);
    short* Kb     = (short*)(ws + WS_KB);
    short* Vtp    = (short*)(ws + WS_VT);

    prep_w<<<dim3(CC), dim3(128), 0, stream>>>(wq, bnq_g, bnq_b, bnq_m, bnq_v, wq_b, bias_q,
                                               wv, wv_b);
    prep_w<<<dim3(CC), dim3(128), 0, stream>>>(wk, bnk_g, bnk_b, bnk_m, bnk_v, wk_b, bias_k,
                                               nullptr, nullptr);

    qkv_conv<<<dim3(DEPTH / 2, BB, 2), dim3(192), 0, stream>>>(
        x, wq_b, wk_b, wv_b, bias_q, bias_k, sg, Qb, Kb, Vtp);

    attn_kernel<<<dim3(NN / 32 * 16), dim3(256), 0, stream>>>(Qb, Kb, Vtp, attw);

    proj_kernel<<<dim3((BB * NN * CC) / 256), dim3(256), 0, stream>>>(attw, wo, bo, (float*)d_out);
}

// Round 16
// 78.478 us; speedup vs baseline: 1.3981x; 1.2267x over previous
//
#include <hip/hip_runtime.h>
#include <hip/hip_bf16.h>

#define BB 4
#define DEPTH 160
#define CC 96
#define NN 2560          // DEPTH*16
#define NHH 4
#define HD 24
#define THETA 0.6f
#define BN_EPS 1e-5f

typedef __attribute__((ext_vector_type(4))) float f32x4;
typedef __attribute__((ext_vector_type(8))) short s16x8;
typedef __attribute__((ext_vector_type(4))) short s16x4;
typedef __attribute__((ext_vector_type(2))) unsigned u32x2;
typedef __attribute__((ext_vector_type(4))) unsigned u32x4;

#if __has_builtin(__builtin_amdgcn_exp2f)
#define EXP2(x) __builtin_amdgcn_exp2f(x)
#else
#define EXP2(x) exp2f(x)
#endif

// ---------------------------------------------------------------------------
// Workspace layout (float slots):
//   wq_b  : bf16 [tap][oc][ic] 27*96*96 shorts  -> 124416 slots (r10 layout)
//   wk_b  : 124416
//   wv_b  : bf16 [oc][ic] 9216 shorts           -> 4608
//   bias_q: 96, bias_k: 96 (fp32)
//   att   : fp32 [b][n][96]                     -> 983040
//   Qb    : bf16 [bh][n][32] (hd 24..31 zeroed) -> 655360
//   Kb    : bf16 [bh][n][32]                    -> 655360
//   Vtp   : bf16 [bh][tile][s*2+dh][16 dims][32 slots] — per-64-key-tile blocked
//   wo_b  : bf16 frag-blocked [oct 6][icb 3][j16 x 32ic] -> 4608 slots
// ---------------------------------------------------------------------------
#define WS_WQ   0
#define WS_WK   124416
#define WS_WV   248832
#define WS_BQ   253440
#define WS_BK   253536
#define WS_ATT  253632
#define WS_QB   1236672
#define WS_KB   1892032
#define WS_VT   2547392
#define WS_WO   3202752

__device__ __forceinline__ short f2bf(float f) {
    unsigned u = __float_as_uint(f);
    u += 0x7fffu + ((u >> 16) & 1u);
    return (short)(u >> 16);
}
__device__ __forceinline__ unsigned bf16pk(float lo, float hi) {
    unsigned r;
    asm("v_cvt_pk_bf16_f32 %0, %1, %2" : "=v"(r) : "v"(lo), "v"(hi));
    return r;
}
// PV slot of key n within its 64-token tile (bit5 = s-half kept, low 5 permuted
// so the P B-fragment is the lane's own QK^T output).
__device__ __forceinline__ int vslot(int n) {
    return (n & 32) | (((n >> 2) & 3) << 3) | (((n >> 4) & 1) << 2) | (n & 3);
}

// Fold TCDC center-tap correction + BN scale into conv weights; bf16 [tap][oc][ic].
// The Q-instance also converts the 1x1x1 V weights (wv/wv_b non-null).
__global__ void prep_w(const float* __restrict__ w, const float* __restrict__ gamma,
                       const float* __restrict__ beta, const float* __restrict__ mean,
                       const float* __restrict__ var, short* __restrict__ w_eff,
                       float* __restrict__ bias,
                       const float* __restrict__ wv, short* __restrict__ wv_b) {
    int oc = blockIdx.x;
    int ic = threadIdx.x;
    if (ic >= CC) return;
    float scale = gamma[oc] * rsqrtf(var[oc] + BN_EPS);
    if (ic == 0) bias[oc] = beta[oc] - mean[oc] * scale;
    const float* wp = w + (oc * CC + ic) * 27;
    float kdiff = 0.f;
#pragma unroll
    for (int t = 0; t < 9; ++t) kdiff += wp[t] + wp[18 + t];
#pragma unroll
    for (int t = 0; t < 27; ++t) {
        float v = wp[t];
        if (t == 13) v -= THETA * kdiff;     // center tap (1,1,1)
        w_eff[t * (CC * CC) + oc * CC + ic] = f2bf(v * scale);
    }
    if (wv_b) wv_b[oc * CC + ic] = f2bf(wv[oc * CC + ic]);
}

// wo -> fragment-blocked bf16 [oct][icb][(oc&15)*32 + (ic&31)]
__global__ void prep_wo(const float* __restrict__ wo, short* __restrict__ wo_b) {
    int i = blockIdx.x * 256 + threadIdx.x;
    if (i < CC * CC) {
        int oc = i / CC, ic = i % CC;
        wo_b[(((oc >> 4) * 3 + (ic >> 5)) << 9) + (oc & 15) * 32 + (ic & 31)] = f2bf(wo[i]);
    }
}

// MFMA im2col conv — r15 (proven): block = (2 depth slices) x (oc-half);
// 3 waves = oct(3); Q+K+V per wave; register double-buffered weight frags.
__global__ __launch_bounds__(192) void qkv_conv(
        const float* __restrict__ x, const short* __restrict__ wq_b,
        const short* __restrict__ wk_b, const short* __restrict__ wv_b,
        const float* __restrict__ bias_q, const float* __restrict__ bias_k,
        const float* __restrict__ sgp,
        short* __restrict__ Qb, short* __restrict__ Kb, short* __restrict__ Vtp) {
    __shared__ __align__(16) short xs[65 * 104];   // 64 rows + zero row, stride 104
    const int b = blockIdx.y;
    const int d0 = blockIdx.x * 2;
    const int z = blockIdx.z;                       // oc-half
    const int tid = threadIdx.x;

    // stage 4 slices (d0-1 .. d0+2), f32 -> bf16 via cvt_pk; 1536 chunks
#pragma unroll
    for (int k = 0; k < 8; ++k) {
        int c = tid + k * 192;
        int row = c / 24, ic0 = (c % 24) * 4;
        int dg = d0 - 1 + (row >> 4), pos = row & 15;
        u32x2 o = {0u, 0u};
        if (dg >= 0 && dg < DEPTH) {
            f32x4 v = *(const f32x4*)(x + ((size_t)(b * NN + dg * 16 + pos)) * CC + ic0);
            o[0] = bf16pk(v[0], v[1]);
            o[1] = bf16pk(v[2], v[3]);
        }
        *(u32x2*)&xs[row * 104 + ic0] = o;
    }
    if (tid < 26) *(u32x2*)&xs[64 * 104 + tid * 4] = (u32x2){0u, 0u};
    __syncthreads();

    const int w  = tid >> 6, l = tid & 63;          // w = oct
    const int j  = l & 15, g = l >> 4;
    const int oc0 = z * 48 + w * 16;
    const int hj = j >> 2, wj = j & 3;

    const short* wqlane = wq_b + (oc0 + j) * CC + 8 * g;
    const short* wklane = wk_b + (oc0 + j) * CC + 8 * g;
    const short* wvlane = wv_b + (oc0 + j) * CC + 8 * g;

    f32x4 accQA = {0,0,0,0}, accQB = {0,0,0,0};
    f32x4 accKA = {0,0,0,0}, accKB = {0,0,0,0};
    f32x4 avA   = {0,0,0,0}, avB   = {0,0,0,0};

    // register double-buffer: current / next tap weight fragments
    s16x8 wqc[3], wkc[3], wqn[3], wkn[3];
#pragma unroll
    for (int icb = 0; icb < 3; ++icb) {
        wqc[icb] = *(const s16x8*)(wqlane + icb * 32);     // tap 0
        wkc[icb] = *(const s16x8*)(wklane + icb * 32);
    }

#pragma unroll
    for (int tap = 0; tap < 27; ++tap) {
        if (tap < 26) {
#pragma unroll
            for (int icb = 0; icb < 3; ++icb) {
                wqn[icb] = *(const s16x8*)(wqlane + (tap + 1) * (CC * CC) + icb * 32);
                wkn[icb] = *(const s16x8*)(wklane + (tap + 1) * (CC * CC) + icb * 32);
            }
        }
        const int kd = tap / 9, kh = (tap / 3) % 3, kw = tap % 3;
        const int hh = hj + kh - 1, ww = wj + kw - 1;
        const bool valid = ((unsigned)hh < 4u) && ((unsigned)ww < 4u);
        const int rA = valid ? (kd * 16 + hh * 4 + ww) : 64;       // slice t=0
        const int rB = valid ? ((1 + kd) * 16 + hh * 4 + ww) : 64; // slice t=1
        const short* xrA = &xs[rA * 104 + 8 * g];
        const short* xrB = &xs[rB * 104 + 8 * g];
#pragma unroll
        for (int icb = 0; icb < 3; ++icb) {
            s16x8 afA = *(const s16x8*)(xrA + icb * 32);
            s16x8 afB = *(const s16x8*)(xrB + icb * 32);
            accQA = __builtin_amdgcn_mfma_f32_16x16x32_bf16(afA, wqc[icb], accQA, 0, 0, 0);
            accQB = __builtin_amdgcn_mfma_f32_16x16x32_bf16(afB, wqc[icb], accQB, 0, 0, 0);
            accKA = __builtin_amdgcn_mfma_f32_16x16x32_bf16(afA, wkc[icb], accKA, 0, 0, 0);
            accKB = __builtin_amdgcn_mfma_f32_16x16x32_bf16(afB, wkc[icb], accKB, 0, 0, 0);
            if (tap == 13) {   // V rides the center tap's A-frags
                s16x8 bv = *(const s16x8*)(wvlane + icb * 32);
                avA = __builtin_amdgcn_mfma_f32_16x16x32_bf16(afA, bv, avA, 0, 0, 0);
                avB = __builtin_amdgcn_mfma_f32_16x16x32_bf16(afB, bv, avB, 0, 0, 0);
            }
        }
        if (tap < 26) {
#pragma unroll
            for (int icb = 0; icb < 3; ++icb) {
                wqc[icb] = wqn[icb];
                wkc[icb] = wkn[icb];
            }
        }
    }

    // epilogue
    const float qs = 1.4426950408889634f / sgp[0];
    const int oc = oc0 + j, h = oc / HD, hd = oc % HD;
    const float bq_ = bias_q[oc], bk_ = bias_k[oc];
    const size_t headbase = (size_t)(b * NHH + h) * NN;
    short* QpA = Qb + (headbase + (d0 + 0) * 16 + 4 * g) * 32 + hd;
    short* QpB = Qb + (headbase + (d0 + 1) * 16 + 4 * g) * 32 + hd;
    short* KpA = Kb + (headbase + (d0 + 0) * 16 + 4 * g) * 32 + hd;
    short* KpB = Kb + (headbase + (d0 + 1) * 16 + 4 * g) * 32 + hd;
#pragma unroll
    for (int r = 0; r < 4; ++r) {
        QpA[r * 32] = f2bf((accQA[r] + bq_) * qs);
        QpB[r * 32] = f2bf((accQB[r] + bq_) * qs);
        KpA[r * 32] = f2bf(accKA[r] + bk_);
        KpB[r * 32] = f2bf(accKB[r] + bk_);
    }
    {
        short* Vb = Vtp + (size_t)(b * NHH + h) * (NN * 32);
        const int dh = hd >> 4, dj = hd & 15;
#pragma unroll
        for (int r = 0; r < 4; ++r) {
            int nA = d0 * 16 + 4 * g + r;
            int nB = nA + 16;
            int wA = vslot(nA & 63), wB = vslot(nB & 63);
            Vb[(nA >> 6) * 2048 + ((wA >> 5) * 2 + dh) * 512 + dj * 32 + (wA & 31)] = f2bf(avA[r]);
            Vb[(nB >> 6) * 2048 + ((wB >> 5) * 2 + dh) * 512 + dj * 32 + (wB & 31)] = f2bf(avB[r]);
        }
    }
    if (z == 0 && w == 0) {
        const int n = (d0 + ((l >> 4) & 1)) * 16 + (l & 15);
        const s16x8 z8 = {0, 0, 0, 0, 0, 0, 0, 0};
#pragma unroll
        for (int it = 0; it < 2; ++it) {
            int h2 = (l >> 5) + 2 * it;
            *(s16x8*)(Qb + ((size_t)(b * NHH + h2) * NN + n) * 32 + 24) = z8;
            *(s16x8*)(Kb + ((size_t)(b * NHH + h2) * NN + n) * 32 + 24) = z8;
        }
        const int wN = vslot(n & 63);
#pragma unroll
        for (int it2 = 0; it2 < 2; ++it2) {
            int h3 = it2 * 2 + (l >> 5);
            short* pb = Vtp + (size_t)(b * NHH + h3) * (NN * 32)
                      + (n >> 6) * 2048 + ((wN >> 5) * 2 + 1) * 512 + (wN & 31);
#pragma unroll
            for (int dj = 8; dj < 16; ++dj)
                pb[dj * 32] = 0;
        }
    }
}

// MFMA flash attention — r10 (proven, byte-identical).
#define SOFTTILE(S0, S1, S2, S3, MX, LP, OA, OB, P0, P1) {                      \
    float v0 = fmaxf(fmaxf(S0[0], S0[1]), fmaxf(S0[2], S0[3]));                 \
    float v1 = fmaxf(fmaxf(S1[0], S1[1]), fmaxf(S1[2], S1[3]));                 \
    float v2 = fmaxf(fmaxf(S2[0], S2[1]), fmaxf(S2[2], S2[3]));                 \
    float v3 = fmaxf(fmaxf(S3[0], S3[1]), fmaxf(S3[2], S3[3]));                 \
    float vmx = fmaxf(fmaxf(v0, v1), fmaxf(v2, v3));                            \
    vmx = fmaxf(vmx, __shfl_xor(vmx, 16));                                      \
    vmx = fmaxf(vmx, __shfl_xor(vmx, 32));                                      \
    float nm = fmaxf(MX, vmx);                                                  \
    float sc = EXP2(MX - nm);                                                   \
    MX = nm;                                                                    \
    LP *= sc; OA *= sc; OB *= sc;                                               \
    float p00 = EXP2(S0[0] - MX), p01 = EXP2(S0[1] - MX);                       \
    float p02 = EXP2(S0[2] - MX), p03 = EXP2(S0[3] - MX);                       \
    float p10 = EXP2(S1[0] - MX), p11 = EXP2(S1[1] - MX);                       \
    float p12 = EXP2(S1[2] - MX), p13 = EXP2(S1[3] - MX);                       \
    float p20 = EXP2(S2[0] - MX), p21 = EXP2(S2[1] - MX);                       \
    float p22 = EXP2(S2[2] - MX), p23 = EXP2(S2[3] - MX);                       \
    float p30 = EXP2(S3[0] - MX), p31 = EXP2(S3[1] - MX);                       \
    float p32 = EXP2(S3[2] - MX), p33 = EXP2(S3[3] - MX);                       \
    LP += (((p00 + p01) + (p02 + p03)) + ((p10 + p11) + (p12 + p13)))           \
        + (((p20 + p21) + (p22 + p23)) + ((p30 + p31) + (p32 + p33)));          \
    u32x4 w0_ = { bf16pk(p00, p01), bf16pk(p02, p03),                           \
                  bf16pk(p10, p11), bf16pk(p12, p13) };                         \
    u32x4 w1_ = { bf16pk(p20, p21), bf16pk(p22, p23),                           \
                  bf16pk(p30, p31), bf16pk(p32, p33) };                         \
    P0 = __builtin_bit_cast(s16x8, w0_);                                        \
    P1 = __builtin_bit_cast(s16x8, w1_);                                        \
}

__global__ __launch_bounds__(256) void attn_kernel(
        const short* __restrict__ Qb, const short* __restrict__ Kb,
        const short* __restrict__ Vtp, float* __restrict__ att) {
    __shared__ __align__(16) float comb[3][64][20];
    const int bh = blockIdx.x & 15;            // pins bh pairs per XCD for L2 reuse
    const int q0 = (blockIdx.x >> 4) * 32;
    const int b = bh >> 2, h = bh & 3;
    const int tid = threadIdx.x, wvid = tid >> 6, l = tid & 63;
    const int j = l & 15, g = l >> 4;

    const s16x8 qf0 = *(const s16x8*)(Qb + ((size_t)bh * NN + q0 + j) * 32 + 8 * g);
    const s16x8 qf1 = *(const s16x8*)(Qb + ((size_t)bh * NN + q0 + 16 + j) * 32 + 8 * g);
    const short* Kbase = Kb  + (size_t)bh * NN * 32 + (size_t)j * 32 + 8 * g;
    const short* Vbase = Vtp + (size_t)bh * NN * 32 + (size_t)j * 32 + 8 * g;

    f32x4 oA0 = {0,0,0,0}, oB0 = {0,0,0,0};    // q-tile 0: O^T dims 4g.. / 16+4g..
    f32x4 oA1 = {0,0,0,0}, oB1 = {0,0,0,0};    // q-tile 1
    float mx0 = -1e30f, lp0 = 0.f, mx1 = -1e30f, lp1 = 0.f;
    const f32x4 z = {0,0,0,0};

    const int tbeg = wvid * (NN / 4);
    const int tend = tbeg + NN / 4;            // 640 keys, 10 tiles per wave

    for (int t0 = tbeg; t0 < tend; t0 += 64) {
        const short* kp = Kbase + (size_t)t0 * 32;
        s16x8 k0 = *(const s16x8*)(kp);
        s16x8 k1 = *(const s16x8*)(kp + 512);
        s16x8 k2 = *(const s16x8*)(kp + 1024);
        s16x8 k3 = *(const s16x8*)(kp + 1536);
        const short* vp = Vbase + (size_t)t0 * 32;     // tile base: t0/64*2048
        s16x8 vA0 = *(const s16x8*)(vp);               // (s0,d0)
        s16x8 vB0 = *(const s16x8*)(vp + 512);         // (s0,d1)
        s16x8 vA1 = *(const s16x8*)(vp + 1024);        // (s1,d0)
        s16x8 vB1 = *(const s16x8*)(vp + 1536);        // (s1,d1)

        f32x4 s0 = __builtin_amdgcn_mfma_f32_16x16x32_bf16(k0, qf0, z, 0, 0, 0);
        f32x4 s1 = __builtin_amdgcn_mfma_f32_16x16x32_bf16(k1, qf0, z, 0, 0, 0);
        f32x4 s2 = __builtin_amdgcn_mfma_f32_16x16x32_bf16(k2, qf0, z, 0, 0, 0);
        f32x4 s3 = __builtin_amdgcn_mfma_f32_16x16x32_bf16(k3, qf0, z, 0, 0, 0);
        s16x8 P00, P01;
        SOFTTILE(s0, s1, s2, s3, mx0, lp0, oA0, oB0, P00, P01)

        f32x4 t0s = __builtin_amdgcn_mfma_f32_16x16x32_bf16(k0, qf1, z, 0, 0, 0);
        f32x4 t1s = __builtin_amdgcn_mfma_f32_16x16x32_bf16(k1, qf1, z, 0, 0, 0);
        f32x4 t2s = __builtin_amdgcn_mfma_f32_16x16x32_bf16(k2, qf1, z, 0, 0, 0);
        f32x4 t3s = __builtin_amdgcn_mfma_f32_16x16x32_bf16(k3, qf1, z, 0, 0, 0);
        s16x8 P10, P11;
        SOFTTILE(t0s, t1s, t2s, t3s, mx1, lp1, oA1, oB1, P10, P11)

        oA0 = __builtin_amdgcn_mfma_f32_16x16x32_bf16(vA0, P00, oA0, 0, 0, 0);
        oA0 = __builtin_amdgcn_mfma_f32_16x16x32_bf16(vA1, P01, oA0, 0, 0, 0);
        oB0 = __builtin_amdgcn_mfma_f32_16x16x32_bf16(vB0, P00, oB0, 0, 0, 0);
        oB0 = __builtin_amdgcn_mfma_f32_16x16x32_bf16(vB1, P01, oB0, 0, 0, 0);
        oA1 = __builtin_amdgcn_mfma_f32_16x16x32_bf16(vA0, P10, oA1, 0, 0, 0);
        oA1 = __builtin_amdgcn_mfma_f32_16x16x32_bf16(vA1, P11, oA1, 0, 0, 0);
        oB1 = __builtin_amdgcn_mfma_f32_16x16x32_bf16(vB0, P10, oB1, 0, 0, 0);
        oB1 = __builtin_amdgcn_mfma_f32_16x16x32_bf16(vB1, P11, oB1, 0, 0, 0);
    }

    // row-sum lp across the 4 g-lanes
    lp0 += __shfl_xor(lp0, 16); lp0 += __shfl_xor(lp0, 32);
    lp1 += __shfl_xor(lp1, 16); lp1 += __shfl_xor(lp1, 32);

    if (wvid != 0) {
        float* cp = comb[wvid - 1][l];
        cp[0] = mx0; cp[1] = lp0; cp[2] = mx1; cp[3] = lp1;
        *(f32x4*)(cp + 4)  = oA0;
        *(f32x4*)(cp + 8)  = oB0;
        *(f32x4*)(cp + 12) = oA1;
        *(f32x4*)(cp + 16) = oB1;
    }
    __syncthreads();
    if (wvid != 0) return;

#pragma unroll
    for (int wv = 0; wv < 3; ++wv) {
        const float* cp = comb[wv][l];
        {
            float mb = cp[0], lb = cp[1];
            f32x4 oAb = *(const f32x4*)(cp + 4);
            f32x4 oBb = *(const f32x4*)(cp + 8);
            float mm = fmaxf(mx0, mb);
            float sa = EXP2(mx0 - mm), sb = EXP2(mb - mm);
            mx0 = mm;
            lp0 = lp0 * sa + lb * sb;
            oA0 = oA0 * sa + oAb * sb;
            oB0 = oB0 * sa + oBb * sb;
        }
        {
            float mb = cp[2], lb = cp[3];
            f32x4 oAb = *(const f32x4*)(cp + 12);
            f32x4 oBb = *(const f32x4*)(cp + 16);
            float mm = fmaxf(mx1, mb);
            float sa = EXP2(mx1 - mm), sb = EXP2(mb - mm);
            mx1 = mm;
            lp1 = lp1 * sa + lb * sb;
            oA1 = oA1 * sa + oAb * sb;
            oB1 = oB1 * sa + oBb * sb;
        }
    }

    const float rl0 = 1.f / lp0, rl1 = 1.f / lp1;
    f32x4 rA0 = oA0 * rl0, rB0 = oB0 * rl0;
    f32x4 rA1 = oA1 * rl1, rB1 = oB1 * rl1;

    float* op0 = att + ((size_t)b * NN + q0 + j) * CC + h * HD;
    float* op1 = att + ((size_t)b * NN + q0 + 16 + j) * CC + h * HD;
    *(f32x4*)(op0 + 4 * g) = rA0;
    *(f32x4*)(op1 + 4 * g) = rA1;
    if (g < 2) {
        *(f32x4*)(op0 + 16 + 4 * g) = rB0;
        *(f32x4*)(op1 + 16 + 4 * g) = rB1;
    }
}

// MFMA out-projection: out[t][c] = bo[c] + sum_ic att[t][ic] * wo[c][ic].
// Block = 64 tokens, 4 waves x 16-token tile. att tile staged to LDS as bf16
// (rows padded to 104 shorts -> 2-way bank alias = free). A-frag = att rows
// (lane j = token j), B-frag = wo_b fragment (lane j = oc j) — identical
// operand convention to qkv_conv (validated). 18 MFMA/wave.
__global__ __launch_bounds__(256) void proj_kernel(
        const float* __restrict__ att, const short* __restrict__ wo_b,
        const float* __restrict__ bo, float* __restrict__ out) {
    __shared__ __align__(16) short als[64 * 104];
    const int t0 = blockIdx.x * 64;
    const int tid = threadIdx.x;
#pragma unroll
    for (int k = 0; k < 6; ++k) {
        int c = tid + k * 256;                      // 1536 chunks
        int row = c / 24, ic0 = (c % 24) * 4;
        f32x4 v = *(const f32x4*)(att + (size_t)(t0 + row) * CC + ic0);
        u32x2 o = { bf16pk(v[0], v[1]), bf16pk(v[2], v[3]) };
        *(u32x2*)&als[row * 104 + ic0] = o;
    }
    __syncthreads();

    const int w = tid >> 6, l = tid & 63;
    const int j = l & 15, g = l >> 4;
    const short* ap = &als[(w * 16 + j) * 104 + 8 * g];
    s16x8 a0 = *(const s16x8*)(ap);
    s16x8 a1 = *(const s16x8*)(ap + 32);
    s16x8 a2 = *(const s16x8*)(ap + 64);
    const f32x4 zz = {0, 0, 0, 0};
    float* ob = out + (size_t)(t0 + w * 16 + 4 * g) * CC + j;
#pragma unroll
    for (int oct = 0; oct < 6; ++oct) {
        const short* wp = wo_b + oct * 3 * 512 + j * 32 + 8 * g;
        f32x4 acc = zz;
        acc = __builtin_amdgcn_mfma_f32_16x16x32_bf16(a0, *(const s16x8*)(wp),        acc, 0, 0, 0);
        acc = __builtin_amdgcn_mfma_f32_16x16x32_bf16(a1, *(const s16x8*)(wp + 512),  acc, 0, 0, 0);
        acc = __builtin_amdgcn_mfma_f32_16x16x32_bf16(a2, *(const s16x8*)(wp + 1024), acc, 0, 0, 0);
        const float bb = bo[oct * 16 + j];
#pragma unroll
        for (int r = 0; r < 4; ++r)
            ob[(size_t)r * CC + oct * 16] = acc[r] + bb;
    }
}

extern "C" void kernel_launch(void* const* d_in, const int* in_sizes, int n_in,
                              void* d_out, int out_size, void* d_ws, size_t ws_size,
                              hipStream_t stream) {
    const float* x     = (const float*)d_in[0];
    const float* sg    = (const float*)d_in[1];
    const float* wq    = (const float*)d_in[2];
    const float* bnq_g = (const float*)d_in[3];
    const float* bnq_b = (const float*)d_in[4];
    const float* bnq_m = (const float*)d_in[5];
    const float* bnq_v = (const float*)d_in[6];
    const float* wk    = (const float*)d_in[7];
    const float* bnk_g = (const float*)d_in[8];
    const float* bnk_b = (const float*)d_in[9];
    const float* bnk_m = (const float*)d_in[10];
    const float* bnk_v = (const float*)d_in[11];
    const float* wv    = (const float*)d_in[12];
    const float* wo    = (const float*)d_in[13];
    const float* bo    = (const float*)d_in[14];

    float* ws = (float*)d_ws;
    short* wq_b   = (short*)(ws + WS_WQ);
    short* wk_b   = (short*)(ws + WS_WK);
    short* wv_b   = (short*)(ws + WS_WV);
    float* bias_q = ws + WS_BQ;
    float* bias_k = ws + WS_BK;
    float* attw   = ws + WS_ATT;
    short* Qb     = (short*)(ws + WS_QB);
    short* Kb     = (short*)(ws + WS_KB);
    short* Vtp    = (short*)(ws + WS_VT);
    short* wo_b   = (short*)(ws + WS_WO);

    prep_w<<<dim3(CC), dim3(128), 0, stream>>>(wq, bnq_g, bnq_b, bnq_m, bnq_v, wq_b, bias_q,
                                               wv, wv_b);
    prep_w<<<dim3(CC), dim3(128), 0, stream>>>(wk, bnk_g, bnk_b, bnk_m, bnk_v, wk_b, bias_k,
                                               nullptr, nullptr);
    prep_wo<<<dim3(36), dim3(256), 0, stream>>>(wo, wo_b);

    qkv_conv<<<dim3(DEPTH / 2, BB, 2), dim3(192), 0, stream>>>(
        x, wq_b, wk_b, wv_b, bias_q, bias_k, sg, Qb, Kb, Vtp);

    attn_kernel<<<dim3(NN / 32 * 16), dim3(256), 0, stream>>>(Qb, Kb, Vtp, attw);

    proj_kernel<<<dim3(BB * NN / 64), dim3(256), 0, stream>>>(attw, wo_b, bo, (float*)d_out);
}